// Round 9
// baseline (2887.686 us; speedup 1.0000x reference)
//
#include <hip/hip_runtime.h>
#include <hip/hip_cooperative_groups.h>
#include <stdint.h>

namespace cg = cooperative_groups;

// DBSCAN, N=16384 points in R^3, eps=0.2, minPts=10.
//
// R9: ONE cooperative kernel (1024 blocks x 256, 4 blocks/CU co-resident).
// R7's verified dataflow, phases separated by grid.sync() instead of kernel
// launches (R3/R6/R7 measured ~12us slack per launch; R7 paid ~70-95us).
// The R7 single-block k_cc_final (63us, VALUBusy 0.1%) is decomposed: all
// heavy CC work is full-grid {hook, jump} rounds over geometrically shrinking
// survivor lists to exact fixpoint; the only single-block residue is ranking
// ~K roots (K ~ tens) in O(K^2/256).
//
// Numerics replicate the reference EXACTLY in fp32 (absmax=0 in R1-R8):
//   sq  = (x*x + y*y) + z*z               (left-to-right)
//   dot = fma(z,z', fma(y,y', x*x'))      (BLAS k-ordered FMA chain)
//   d2  = (sq_i + sq_j) - 2.0f*dot ; adj = d2 < 0.04f
// Min-index hooking => component root == min core index == reference's
// min-label fixpoint; roots ranked ascending == scan-order cluster ids;
// border label = rank[min neighbor root] (rank monotone in root index).

#define N_PTS   16384
#define BLOCK   256
#define GBLKS   1024
#define GT      (GBLKS * BLOCK)
#define IPT     4
#define ITILE   1024                    // IPT * BLOCK
#define JT      128
#define NTI     (N_PTS / ITILE)         // 16
#define NTILES  (4 * NTI * (NTI + 1))   // 1088 triangular tiles
#define EPS2    0.04f
#define MINPTS  10
#define ECAP    262144
#define CCAP    262144
#define MCAP    65536
#define SCAP    131072
#define RCAP    4096
#define LBUF    1024
#define BIG     N_PTS

__device__ __forceinline__ float sqsum(float x, float y, float z) {
    return __fadd_rn(__fadd_rn(__fmul_rn(x, x), __fmul_rn(y, y)), __fmul_rn(z, z));
}
__device__ __forceinline__ float dist2(float px, float py, float pz, float sqi, float4 q) {
    float dot = __fmaf_rn(pz, q.z, __fmaf_rn(py, q.y, __fmul_rn(px, q.x)));
    return __fsub_rn(__fadd_rn(sqi, q.w), __fmul_rn(2.0f, dot));
}
__device__ __forceinline__ int pload(const int* p) {
    return __hip_atomic_load(p, __ATOMIC_RELAXED, __HIP_MEMORY_SCOPE_AGENT);
}
__device__ __forceinline__ void jump1(int* parent, int x) {
    int p = pload(&parent[x]);
    if (p == x) return;
    int r = p;
    while (true) { int q = pload(&parent[r]); if (q == r) break; r = q; }
    if (r != p)
        __hip_atomic_store(&parent[x], r, __ATOMIC_RELAXED, __HIP_MEMORY_SCOPE_AGENT);
}

#define GSYNC() do { __threadfence(); grid.sync(); __threadfence(); } while (0)

// cnts slots: 0=tileCtr 1=gcnt 2=ccnt 3=mcnt 4=scntA 5=scntB 6=rootcnt
__global__ void __launch_bounds__(BLOCK, 4)
k_all(const float* __restrict__ pts,
      int* __restrict__ deg, int* __restrict__ rm, int* __restrict__ parent,
      int* __restrict__ rank, int* __restrict__ cnts,
      uint32_t* __restrict__ edges, uint32_t* __restrict__ cclist,
      uint32_t* __restrict__ mbuf, uint32_t* __restrict__ survA,
      uint32_t* __restrict__ survB, int* __restrict__ rootlist,
      float* __restrict__ out) {
    cg::grid_group grid = cg::this_grid();
    __shared__ float4 sj[JT];
    __shared__ int sdeg[JT];
    __shared__ uint32_t lbuf[LBUF];
    __shared__ int s_stile, s_lcnt, s_lbase;

    const int tid = threadIdx.x;
    const int gtid = blockIdx.x * BLOCK + tid;
    const int lane = tid & 63;
    const uint64_t lane_lt = (1ull << lane) - 1;

    // ---- P0: init ----------------------------------------------------------
    if (gtid < N_PTS) { deg[gtid] = 1; rm[gtid] = BIG; parent[gtid] = gtid; }
    if (gtid < 16) cnts[gtid] = 0;
    GSYNC();

    // ---- P1: edges (work-stolen triangular tiles, R7 config) ---------------
    while (true) {
        __syncthreads();                          // protect sj/lbuf reuse
        if (tid == 0) { s_stile = atomicAdd(&cnts[0], 1); s_lcnt = 0; }
        __syncthreads();
        const int b = s_stile;
        if (b >= NTILES) break;
        float tt = sqrtf((float)b + 1.0f);
        int bi = (int)((tt - 1.0f) * 0.5f);
        while (4 * (bi + 1) * (bi + 2) <= b) ++bi;
        while (4 * bi * (bi + 1) > b) --bi;
        const int jc = b - 4 * bi * (bi + 1);
        const int i0 = bi * ITILE, j0 = jc * JT;
        const bool diag = (jc >= 8 * bi);
        if (tid < JT) {
            int j = j0 + tid;
            float x = pts[3 * j], y = pts[3 * j + 1], z = pts[3 * j + 2];
            sj[tid] = make_float4(x, y, z, sqsum(x, y, z));
            sdeg[tid] = 0;
        }
        __syncthreads();
        float px[IPT], py[IPT], pz[IPT], sqi[IPT];
        int ii[IPT], cnt[IPT];
#pragma unroll
        for (int k = 0; k < IPT; ++k) {
            int i = i0 + k * BLOCK + tid;
            ii[k] = i;
            px[k] = pts[3 * i]; py[k] = pts[3 * i + 1]; pz[k] = pts[3 * i + 2];
            sqi[k] = sqsum(px[k], py[k], pz[k]);
            cnt[k] = 0;
        }
        if (!diag) {                               // jg < i guaranteed
#pragma unroll 4
            for (int j = 0; j < JT; ++j) {
                float4 q = sj[j];
                int jg = j0 + j;
#pragma unroll
                for (int k = 0; k < IPT; ++k) {
                    float d2 = dist2(px[k], py[k], pz[k], sqi[k], q);
                    if (d2 < EPS2) {
                        int s = atomicAdd(&s_lcnt, 1);
                        if (s < LBUF) lbuf[s] = ((uint32_t)ii[k] << 14) | (uint32_t)jg;
                        ++cnt[k];
                        atomicAdd(&sdeg[j], 1);
                    }
                }
            }
        } else {
#pragma unroll 4
            for (int j = 0; j < JT; ++j) {
                float4 q = sj[j];
                int jg = j0 + j;
#pragma unroll
                for (int k = 0; k < IPT; ++k) {
                    float d2 = dist2(px[k], py[k], pz[k], sqi[k], q);
                    if (d2 < EPS2 && jg < ii[k]) {
                        int s = atomicAdd(&s_lcnt, 1);
                        if (s < LBUF) lbuf[s] = ((uint32_t)ii[k] << 14) | (uint32_t)jg;
                        ++cnt[k];
                        atomicAdd(&sdeg[j], 1);
                    }
                }
            }
        }
#pragma unroll
        for (int k = 0; k < IPT; ++k)
            if (cnt[k]) atomicAdd(&deg[ii[k]], cnt[k]);
        __syncthreads();
        if (tid < JT && sdeg[tid]) atomicAdd(&deg[j0 + tid], sdeg[tid]);
        if (tid == 0) {
            int nn = min(s_lcnt, LBUF);
            s_lcnt = nn;
            s_lbase = atomicAdd(&cnts[1], nn);
        }
        __syncthreads();
        for (int t2 = tid; t2 < s_lcnt; t2 += BLOCK) {
            int s = s_lbase + t2;
            if (s < ECAP) edges[s] = lbuf[t2];
        }
    }
    GSYNC();

    // ---- P2: hook0 — classify all edges, hook core-core --------------------
    {
        const int n = min(pload(&cnts[1]), ECAP);
        for (int e = gtid; e < n; e += GT) {
            uint32_t p = edges[e];
            int i = (int)(p >> 14), j = (int)(p & (N_PTS - 1));
            bool ci = deg[i] >= MINPTS, cj = deg[j] >= MINPTS;
            bool cc = ci && cj, mx = ci != cj;
            if (cc) atomicMin(&parent[max(i, j)], min(i, j));  // fire-and-forget
            uint64_t m1 = __ballot(cc);
            if (m1) {
                int ldr = (int)__ffsll((unsigned long long)m1) - 1;
                int base = 0;
                if (lane == ldr) base = atomicAdd(&cnts[2], (int)__popcll(m1));
                base = __shfl(base, ldr);
                if (cc) {
                    int pos = base + (int)__popcll(m1 & lane_lt);
                    if (pos < CCAP) cclist[pos] = p;
                }
            }
            uint64_t m2 = __ballot(mx);
            if (m2) {
                int ldr = (int)__ffsll((unsigned long long)m2) - 1;
                int base = 0;
                if (lane == ldr) base = atomicAdd(&cnts[3], (int)__popcll(m2));
                base = __shfl(base, ldr);
                if (mx) {
                    uint32_t pk = ci ? (((uint32_t)i << 14) | (uint32_t)j)
                                     : (((uint32_t)j << 14) | (uint32_t)i); // core<<14|border
                    int pos = base + (int)__popcll(m2 & lane_lt);
                    if (pos < MCAP) mbuf[pos] = pk;
                }
            }
        }
    }
    GSYNC();
    if (gtid < N_PTS) jump1(parent, gtid);
    GSYNC();

    // ---- P3: SV hook+jump rounds over shrinking survivor lists -------------
    {
        const uint32_t* cur = cclist;
        int curN = min(pload(&cnts[2]), CCAP);
        uint32_t* nxt = survA;
        int slot = 4;
        for (int round = 0; round < 24; ++round) {
            for (int e = gtid; e < curN; e += GT) {
                uint32_t p = cur[e];
                int ri = pload(&parent[(int)(p >> 14)]);
                int rj = pload(&parent[(int)(p & (N_PTS - 1))]);
                bool live = (ri != rj);
                int lo = min(ri, rj), hi = max(ri, rj);
                if (live) atomicMin(&parent[hi], lo);
                uint64_t m = __ballot(live);
                if (m) {
                    int ldr = (int)__ffsll((unsigned long long)m) - 1;
                    int base = 0;
                    if (lane == ldr) base = atomicAdd(&cnts[slot], (int)__popcll(m));
                    base = __shfl(base, ldr);
                    if (live) {
                        int pos = base + (int)__popcll(m & lane_lt);
                        if (pos < SCAP) nxt[pos] = ((uint32_t)hi << 14) | (uint32_t)lo;
                    }
                }
            }
            GSYNC();
            if (gtid < N_PTS) jump1(parent, gtid);
            if (gtid == 0) cnts[slot ^ 1] = 0;     // reset buffer used 2 rounds on
            GSYNC();
            int n2 = pload(&cnts[slot]);
            if (n2 == 0) break;                    // uniform across grid
            curN = min(n2, SCAP);
            cur = nxt;
            nxt = (slot == 4) ? survB : survA;
            slot ^= 1;
        }
    }

    // ---- P4: border root-min + root collection -----------------------------
    {
        int nm = min(pload(&cnts[3]), MCAP);
        for (int e = gtid; e < nm; e += GT) {
            uint32_t p = mbuf[e];
            int c = (int)(p >> 14), b2 = (int)(p & (N_PTS - 1));
            atomicMin(&rm[b2], pload(&parent[c]));  // parent[c] = final root
        }
        if (gtid < N_PTS && deg[gtid] >= MINPTS && pload(&parent[gtid]) == gtid) {
            int pos = atomicAdd(&cnts[6], 1);
            if (pos < RCAP) rootlist[pos] = gtid;
        }
    }
    GSYNC();

    // ---- P5: rank the K roots (ascending index == scan order), block 0 -----
    if (blockIdx.x == 0) {
        int K = min(pload(&cnts[6]), RCAP);
        for (int r = tid; r < K && r < LBUF; r += BLOCK) lbuf[r] = (uint32_t)rootlist[r];
        __syncthreads();
        for (int r = tid; r < K; r += BLOCK) {
            int v = rootlist[r];
            int c = 0;
            for (int j2 = 0; j2 < K; ++j2) {
                int u = (j2 < LBUF) ? (int)lbuf[j2] : rootlist[j2];
                c += (u < v) ? 1 : 0;
            }
            rank[v] = c;
        }
    }
    GSYNC();

    // ---- P6: labels --------------------------------------------------------
    if (gtid < N_PTS) {
        float o;
        if (deg[gtid] >= MINPTS) {
            o = (float)rank[pload(&parent[gtid])];
        } else {
            int rv = pload(&rm[gtid]);
            o = (rv < BIG) ? (float)rank[rv] : -1.0f;
        }
        out[gtid] = o;
    }
}

// ---------------------------------------------------------------------------
extern "C" void kernel_launch(void* const* d_in, const int* in_sizes, int n_in,
                              void* d_out, int out_size, void* d_ws, size_t ws_size,
                              hipStream_t stream) {
    (void)in_sizes; (void)n_in; (void)out_size; (void)ws_size;
    const float* pts = (const float*)d_in[0];
    float* out = (float*)d_out;

    int* ib = (int*)d_ws;
    int*      deg      = ib;                       // N
    int*      rm       = deg + N_PTS;              // N
    int*      parent   = rm + N_PTS;               // N
    int*      rank     = parent + N_PTS;           // N
    int*      cnts     = rank + N_PTS;             // 64
    int*      rootlist = cnts + 64;                // RCAP
    uint32_t* edges    = (uint32_t*)(rootlist + RCAP);
    uint32_t* cclist   = edges + ECAP;
    uint32_t* mbuf     = cclist + CCAP;
    uint32_t* survA    = mbuf + MCAP;
    uint32_t* survB    = survA + SCAP;             // total ~3.7 MB

    void* args[] = { (void*)&pts, (void*)&deg, (void*)&rm, (void*)&parent,
                     (void*)&rank, (void*)&cnts, (void*)&edges, (void*)&cclist,
                     (void*)&mbuf, (void*)&survA, (void*)&survB, (void*)&rootlist,
                     (void*)&out };
    hipLaunchCooperativeKernel((void*)k_all, dim3(GBLKS), dim3(BLOCK),
                               args, 0, stream);
}

// Round 10
// 280.414 us; speedup vs baseline: 10.2979x; 10.2979x over previous
//
#include <hip/hip_runtime.h>
#include <stdint.h>

// DBSCAN, N=16384 points in R^3, eps=0.2, minPts=10.
//
// R10 (5 launches) — R7's verified dataflow, two structural trims:
//   k_init      : deg=1, parent=i, counters=0
//   k_edges     : packed-triangular N^2 (i-tile 1024/IPT=4 x j-tile 128,
//                 1088 blocks, diagonal specialization) -> edges + degrees
//   k_hook0     : full-grid classify: core-core -> cclist + fire-and-forget
//                 atomicMin hook on raw endpoints; mixed -> mbuf
//   k_jumphook1 : FUSED (was k_jump + k_hook1): per-node root jump, then
//                 grid-stride cclist with CHASED-root hooking + survivor
//                 append. Chasing makes the missing barrier safe: hook
//                 targets are momentary roots (link-free slots), every live
//                 edge re-appends its root pair, drops only on observed
//                 common ancestor -> no connectivity lost (R5-R7 invariant).
//   k_cc_final  : ONE block: parent->LDS (borders=BIG), wavefront compress,
//                 contraction rounds on survivors to exact fixpoint, then
//                 R8-style ALL-LDS finale: roots re-encoded in place as
//                 ENCB+rank, cores -> root code, borders take LDS atomicMin
//                 of neighbor codes (rank monotone in root index => min code
//                 == min root == reference semantics), direct label write.
//
// R9 lesson: grid.sync() at 1024 blocks costs ~150us on MI355X (software
// barrier across 8 non-coherent XCDs) — kernel boundaries (~10us) are the
// cheap barrier; never use cooperative sync here.
//
// Numerics replicate the reference EXACTLY in fp32 (absmax=0 in R1-R9):
//   sq  = (x*x + y*y) + z*z               (left-to-right)
//   dot = fma(z,z', fma(y,y', x*x'))      (BLAS k-ordered FMA chain)
//   d2  = (sq_i + sq_j) - 2.0f*dot ; adj = d2 < 0.04f

#define N_PTS   16384
#define BLOCK   256
#define IPT     4
#define ITILE   1024                    // IPT * BLOCK
#define JT      128
#define NTI     (N_PTS / ITILE)         // 16
#define NBLK    (4 * NTI * (NTI + 1))   // 1088 triangular tiles
#define EPS2    0.04f
#define MINPTS  10
#define ECAP    262144
#define CCAP    262144
#define MCAP    65536
#define SCAP    131072
#define BCAP    131072
#define LBUF    1024
#define NCC     1024
#define CHUNK   (N_PTS / NCC)           // 16
#define BIG     N_PTS                   // border sentinel in LDS parent
#define ENCB    16400                   // cluster-code base (> BIG)
#define HUGEV   (1 << 29)               // noise sentinel after re-encoding

__device__ __forceinline__ float sqsum(float x, float y, float z) {
    return __fadd_rn(__fadd_rn(__fmul_rn(x, x), __fmul_rn(y, y)), __fmul_rn(z, z));
}
__device__ __forceinline__ float dist2(float px, float py, float pz, float sqi, float4 q) {
    float dot = __fmaf_rn(pz, q.z, __fmaf_rn(py, q.y, __fmul_rn(px, q.x)));
    return __fsub_rn(__fadd_rn(sqi, q.w), __fmul_rn(2.0f, dot));
}
__device__ __forceinline__ int pload(const int* p) {
    return __hip_atomic_load(p, __ATOMIC_RELAXED, __HIP_MEMORY_SCOPE_AGENT);
}
// chase to momentary root; parent values strictly decrease -> terminates
__device__ __forceinline__ int chase(int* parent, int x) {
    int r = pload(&parent[x]);
    while (true) { int q = pload(&parent[r]); if (q == r) break; r = q; }
    return r;
}

// ---------------------------------------------------------------------------
__global__ void k_init(int* __restrict__ deg, int* __restrict__ parent,
                       int* __restrict__ cnts) {
    int i = blockIdx.x * BLOCK + threadIdx.x;
    deg[i] = 1;            // self-neighbor (d=0 < eps)
    parent[i] = i;
    if (i < 8) cnts[i] = 0;   // 0=gcnt 1=ccnt 2=mcnt 3=scnt
}

// Packed triangular N^2: i-tile 1024, j-tile 128 (R7 verbatim).
__global__ void k_edges(const float* __restrict__ pts,
                        uint32_t* __restrict__ edges, int* __restrict__ gcnt,
                        int* __restrict__ deg) {
    int b = blockIdx.x;
    float t = sqrtf((float)b + 1.0f);
    int bi = (int)((t - 1.0f) * 0.5f);
    while (4 * (bi + 1) * (bi + 2) <= b) ++bi;
    while (4 * bi * (bi + 1) > b) --bi;
    int jc = b - 4 * bi * (bi + 1);
    const int i0 = bi * ITILE, j0 = jc * JT;
    const bool diag = (jc >= 8 * bi);

    __shared__ float4 sj[JT];
    __shared__ int sdeg[JT];
    __shared__ uint32_t lbuf[LBUF];
    __shared__ int lcnt, lbase;
    const int tid = threadIdx.x;
    if (tid == 0) lcnt = 0;
    if (tid < JT) {
        int j = j0 + tid;
        float x = pts[3 * j], y = pts[3 * j + 1], z = pts[3 * j + 2];
        sj[tid] = make_float4(x, y, z, sqsum(x, y, z));
        sdeg[tid] = 0;
    }
    __syncthreads();
    float px[IPT], py[IPT], pz[IPT], sqi[IPT];
    int ii[IPT], cnt[IPT];
#pragma unroll
    for (int k = 0; k < IPT; ++k) {
        int i = i0 + k * BLOCK + tid;
        ii[k] = i;
        px[k] = pts[3 * i]; py[k] = pts[3 * i + 1]; pz[k] = pts[3 * i + 2];
        sqi[k] = sqsum(px[k], py[k], pz[k]);
        cnt[k] = 0;
    }
    if (!diag) {                                  // jg < i guaranteed
#pragma unroll 4
        for (int j = 0; j < JT; ++j) {
            float4 q = sj[j];
            int jg = j0 + j;
#pragma unroll
            for (int k = 0; k < IPT; ++k) {
                float d2 = dist2(px[k], py[k], pz[k], sqi[k], q);
                if (d2 < EPS2) {
                    int s = atomicAdd(&lcnt, 1);
                    if (s < LBUF) lbuf[s] = ((uint32_t)ii[k] << 14) | (uint32_t)jg;
                    ++cnt[k];
                    atomicAdd(&sdeg[j], 1);
                }
            }
        }
    } else {
#pragma unroll 4
        for (int j = 0; j < JT; ++j) {
            float4 q = sj[j];
            int jg = j0 + j;
#pragma unroll
            for (int k = 0; k < IPT; ++k) {
                float d2 = dist2(px[k], py[k], pz[k], sqi[k], q);
                if (d2 < EPS2 && jg < ii[k]) {
                    int s = atomicAdd(&lcnt, 1);
                    if (s < LBUF) lbuf[s] = ((uint32_t)ii[k] << 14) | (uint32_t)jg;
                    ++cnt[k];
                    atomicAdd(&sdeg[j], 1);
                }
            }
        }
    }
#pragma unroll
    for (int k = 0; k < IPT; ++k)
        if (cnt[k]) atomicAdd(&deg[ii[k]], cnt[k]);
    __syncthreads();
    if (tid < JT && sdeg[tid]) atomicAdd(&deg[j0 + tid], sdeg[tid]);
    if (tid == 0) {
        int n = min(lcnt, LBUF);
        lcnt = n;
        lbase = atomicAdd(gcnt, n);
    }
    __syncthreads();
    for (int t2 = tid; t2 < lcnt; t2 += BLOCK) {
        int s = lbase + t2;
        if (s < ECAP) edges[s] = lbuf[t2];
    }
}

// Full-grid: classify raw edges via deg; hook core-core; build cclist + mbuf.
__global__ void k_hook0(const uint32_t* __restrict__ edges, const int* __restrict__ gcnt,
                        const int* __restrict__ deg, int* __restrict__ parent,
                        uint32_t* __restrict__ cclist, int* __restrict__ ccnt,
                        uint32_t* __restrict__ mbuf, int* __restrict__ mcnt) {
    const int n = min(pload(gcnt), ECAP);
    const int lane = threadIdx.x & 63;
    const uint64_t lane_lt = (1ull << lane) - 1;
    for (int e = blockIdx.x * BLOCK + threadIdx.x; e < n; e += gridDim.x * BLOCK) {
        uint32_t p = edges[e];
        int i = (int)(p >> 14), j = (int)(p & (N_PTS - 1));
        bool ci = deg[i] >= MINPTS, cj = deg[j] >= MINPTS;
        bool cc = ci && cj, mx = ci != cj;
        if (cc) atomicMin(&parent[max(i, j)], min(i, j));  // fire-and-forget
        uint64_t m1 = __ballot(cc);
        if (m1) {
            int ldr = (int)__ffsll((unsigned long long)m1) - 1;
            int base = 0;
            if (lane == ldr) base = atomicAdd(ccnt, (int)__popcll(m1));
            base = __shfl(base, ldr);
            if (cc) {
                int pos = base + (int)__popcll(m1 & lane_lt);
                if (pos < CCAP) cclist[pos] = p;
            }
        }
        uint64_t m2 = __ballot(mx);
        if (m2) {
            int ldr = (int)__ffsll((unsigned long long)m2) - 1;
            int base = 0;
            if (lane == ldr) base = atomicAdd(mcnt, (int)__popcll(m2));
            base = __shfl(base, ldr);
            if (mx) {
                uint32_t pk = ci ? (((uint32_t)i << 14) | (uint32_t)j)
                                 : (((uint32_t)j << 14) | (uint32_t)i);  // core<<14|border
                int pos = base + (int)__popcll(m2 & lane_lt);
                if (pos < MCAP) mbuf[pos] = pk;
            }
        }
    }
}

// FUSED jump + hook1: per-node path shortcut, then chased-root hooking over
// cclist with survivor append. No barrier needed (see header comment).
__global__ void k_jumphook1(const uint32_t* __restrict__ cclist, const int* __restrict__ ccnt,
                            int* __restrict__ parent,
                            uint32_t* __restrict__ surv, int* __restrict__ scnt) {
    const int gtid = blockIdx.x * BLOCK + threadIdx.x;
    const int lane = threadIdx.x & 63;
    const uint64_t lane_lt = (1ull << lane) - 1;
    if (gtid < N_PTS) {
        // path shortcut: store an ancestor (root-at-read) — always safe
        int p = pload(&parent[gtid]);
        if (p != gtid) {
            int r = p;
            while (true) { int q = pload(&parent[r]); if (q == r) break; r = q; }
            if (r != p)
                __hip_atomic_store(&parent[gtid], r, __ATOMIC_RELAXED, __HIP_MEMORY_SCOPE_AGENT);
        }
    }
    const int n = min(pload(ccnt), CCAP);
    const int total = gridDim.x * BLOCK;
    for (int e = gtid; e < n; e += total) {
        uint32_t p = cclist[e];
        int ri = chase(parent, (int)(p >> 14));
        int rj = chase(parent, (int)(p & (N_PTS - 1)));
        bool live = (ri != rj);
        int lo = min(ri, rj), hi = max(ri, rj);
        if (live) atomicMin(&parent[hi], lo);      // target momentary root
        uint64_t m = __ballot(live);
        if (m) {
            int ldr = (int)__ffsll((unsigned long long)m) - 1;
            int base = 0;
            if (lane == ldr) base = atomicAdd(scnt, (int)__popcll(m));
            base = __shfl(base, ldr);
            if (live) {
                int pos = base + (int)__popcll(m & lane_lt);
                if (pos < SCAP) surv[pos] = ((uint32_t)hi << 14) | (uint32_t)lo;
            }
        }
    }
}

// ---------------------------------------------------------------------------
__global__ void __launch_bounds__(NCC)
k_cc_final(const int* __restrict__ parent_g, const int* __restrict__ deg,
           const uint32_t* __restrict__ surv, const int* __restrict__ scnt,
           const uint32_t* __restrict__ mbuf, const int* __restrict__ mcnt,
           uint32_t* __restrict__ bufA, uint32_t* __restrict__ bufB,
           float* __restrict__ out) {
    __shared__ int parent[N_PTS];                  // 64 KB
    __shared__ int s_nout;
    __shared__ int wsum[16];
    const int tid = threadIdx.x, lane = tid & 63, wv = tid >> 6;
    const uint64_t lane_lt = (1ull << lane) - 1;

#pragma unroll
    for (int k = 0; k < CHUNK; ++k) {
        int x = k * NCC + tid;                     // coalesced
        parent[x] = (deg[x] >= MINPTS) ? parent_g[x] : BIG;
    }
    __syncthreads();
    // initial compress: wavefront chase, 16 independent streams per thread
    {
        int v[CHUNK];
#pragma unroll
        for (int k = 0; k < CHUNK; ++k) v[k] = parent[k * NCC + tid];
        bool any = true;
        while (any) {
            any = false;
#pragma unroll
            for (int k = 0; k < CHUNK; ++k) {
                if (v[k] < BIG) {
                    int q = parent[v[k]];
                    if (q != v[k]) { v[k] = q; any = true; }
                }
            }
        }
#pragma unroll
        for (int k = 0; k < CHUNK; ++k)
            if (v[k] < BIG) parent[k * NCC + tid] = v[k];
    }
    __syncthreads();

    // contraction rounds to exact fixpoint over the survivor list
    int n_in = min(pload(scnt), SCAP);
    const uint32_t* cur = surv;
    for (int r = 0; r < 24; ++r) {
        uint32_t* nxt = (r & 1) ? bufB : bufA;
        if (tid == 0) s_nout = 0;
        __syncthreads();
        const int n4 = (n_in + 3) & ~3;
        for (int bb = tid * 4; bb < n4; bb += NCC * 4) {
            uint4 pk = *(const uint4*)(cur + bb);
#pragma unroll
            for (int k = 0; k < 4; ++k) {
                uint32_t p = (k == 0) ? pk.x : (k == 1) ? pk.y : (k == 2) ? pk.z : pk.w;
                bool valid = (bb + k) < n_in;
                int ri = 0, rj = 0;
                if (valid) {
                    ri = parent[(int)(p >> 14)];
                    rj = parent[(int)(p & (N_PTS - 1))];
                }
                bool live = valid && (ri != rj);
                int lo = min(ri, rj), hi = max(ri, rj);
                if (live) atomicMin(&parent[hi], lo);       // LDS fire-and-forget
                uint64_t m = __ballot(live);
                if (m) {
                    int ldr = (int)__ffsll((unsigned long long)m) - 1;
                    int base = 0;
                    if (lane == ldr) base = atomicAdd(&s_nout, (int)__popcll(m));
                    base = __shfl(base, ldr);
                    if (live) {
                        int pos = base + (int)__popcll(m & lane_lt);
                        if (pos < BCAP) nxt[pos] = ((uint32_t)hi << 14) | (uint32_t)lo;
                    }
                }
            }
        }
        __syncthreads();
        int v[CHUNK];
#pragma unroll
        for (int k = 0; k < CHUNK; ++k) v[k] = parent[k * NCC + tid];
        bool any = true;
        while (any) {
            any = false;
#pragma unroll
            for (int k = 0; k < CHUNK; ++k) {
                if (v[k] < BIG) {
                    int q = parent[v[k]];
                    if (q != v[k]) { v[k] = q; any = true; }
                }
            }
        }
#pragma unroll
        for (int k = 0; k < CHUNK; ++k)
            if (v[k] < BIG) parent[k * NCC + tid] = v[k];
        __syncthreads();
        if (s_nout == 0) break;                    // uniform
        n_in = min(s_nout, BCAP);
        cur = nxt;
    }

    // D1: rank roots ascending; re-encode root slots in place as ENCB+rank
    const int bn = tid * CHUNK;
    int fl[CHUNK]; int s = 0;
#pragma unroll
    for (int k = 0; k < CHUNK; ++k) {
        fl[k] = (parent[bn + k] == bn + k) ? 1 : 0;   // borders hold BIG != index
        s += fl[k];
    }
    int incl = s;
#pragma unroll
    for (int d = 1; d < 64; d <<= 1) { int t = __shfl_up(incl, d, 64); if (lane >= d) incl += t; }
    if (lane == 63) wsum[wv] = incl;
    __syncthreads();
    int wbase = 0;
    for (int w = 0; w < wv; ++w) wbase += wsum[w];
    int c = wbase + incl - s;
#pragma unroll
    for (int k = 0; k < CHUNK; ++k)
        if (fl[k]) parent[bn + k] = ENCB + (c++);
    __syncthreads();
    // D2: non-root cores -> root's code; borders -> HUGE sentinel
#pragma unroll
    for (int k = 0; k < CHUNK; ++k) {
        int x = k * NCC + tid;
        int p = parent[x];
        if (p < BIG) parent[x] = parent[p];        // root slots stable (>= ENCB)
        else if (p == BIG) parent[x] = HUGEV;
    }
    __syncthreads();
    // C: border labels = min neighbor-cluster code (rank monotone in root)
    int nm = min(pload(mcnt), MCAP);
    for (int e = tid; e < nm; e += NCC) {
        uint32_t p = mbuf[e];
        int cc = (int)(p >> 14), bb = (int)(p & (N_PTS - 1));
        atomicMin(&parent[bb], parent[cc]);        // LDS
    }
    __syncthreads();
    // E: labels
#pragma unroll
    for (int k = 0; k < CHUNK; ++k) {
        int x = k * NCC + tid;                     // coalesced store
        int v = parent[x];
        out[x] = (v < HUGEV) ? (float)(v - ENCB) : -1.0f;
    }
}

// ---------------------------------------------------------------------------
extern "C" void kernel_launch(void* const* d_in, const int* in_sizes, int n_in,
                              void* d_out, int out_size, void* d_ws, size_t ws_size,
                              hipStream_t stream) {
    (void)in_sizes; (void)n_in; (void)out_size; (void)ws_size;
    const float* pts = (const float*)d_in[0];
    float* out = (float*)d_out;

    // ws layout (words; all list offsets multiples of 16 -> uint4-safe)
    int* ib = (int*)d_ws;
    int*      deg    = ib;                         // 16384
    int*      parent = deg + N_PTS;                // 16384
    int*      cnts   = parent + N_PTS;             // 64
    int*      gcnt = cnts + 0, *ccnt = cnts + 1, *mcnt = cnts + 2, *scnt = cnts + 3;
    uint32_t* edges  = (uint32_t*)(cnts + 64);     // 262144
    uint32_t* cclist = edges + ECAP;               // 262144
    uint32_t* mbuf   = cclist + CCAP;              // 65536
    uint32_t* surv   = mbuf + MCAP;                // 131072
    uint32_t* bufA   = surv + SCAP;                // 131072
    uint32_t* bufB   = bufA + BCAP;                // 131072  (~3.7 MB total)

    dim3 blk(BLOCK);
    dim3 gN(N_PTS / BLOCK);                        // 64
    k_init     <<<gN, blk, 0, stream>>>(deg, parent, cnts);
    k_edges    <<<dim3(NBLK), blk, 0, stream>>>(pts, edges, gcnt, deg);
    k_hook0    <<<dim3(256), blk, 0, stream>>>(edges, gcnt, deg, parent,
                                               cclist, ccnt, mbuf, mcnt);
    k_jumphook1<<<dim3(256), blk, 0, stream>>>(cclist, ccnt, parent, surv, scnt);
    k_cc_final <<<dim3(1), dim3(NCC), 0, stream>>>(parent, deg, surv, scnt,
                                                   mbuf, mcnt, bufA, bufB, out);
}

// Round 11
// 205.643 us; speedup vs baseline: 14.0422x; 1.3636x over previous
//
#include <hip/hip_runtime.h>
#include <stdint.h>

// DBSCAN, N=16384 points in R^3, eps=0.2, minPts=10.
//
// R11 (6 launches) — R7's verified split structure (fusion reverted: R10's
// chased-root hook was a dependent-load chain at 5% occupancy = 148us; the
// kernel-boundary barrier + flat endpoint reads is the fast shape), plus
// R10's all-LDS k_cc_final finale and wider hook grids.
//   k_init   : deg=1, parent=i, counters=0
//   k_edges  : packed-triangular N^2 (i-tile 1024/IPT=4 x j-tile 128,
//              1088 blocks, diagonal specialization) -> edges + degrees
//   k_hook0  : full-grid classify: core-core -> cclist + fire-and-forget
//              atomicMin hook on raw endpoints; mixed -> mbuf  (1024 blocks)
//   k_jump   : parent[x] = root(x)  (one chase per node, 16k threads)
//   k_hook1  : hook FLAT-READ root pairs of cclist, append still-differing
//              survivors (1024 blocks)
//   k_cc_final: ONE block: parent->LDS (borders=BIG), wavefront compress,
//              contraction rounds to exact fixpoint, then all-LDS finale:
//              roots re-encoded in place as ENCB+rank, cores -> root code,
//              borders take LDS atomicMin of neighbor codes (rank monotone
//              in root index => min code == min root == reference
//              semantics), direct label write.
//
// Hard-won constraints (R2/R9/R10): no device-scope CAS retry loops; no
// grid.sync (~150us/sync on MI355X); no dependent pointer-chases in wide
// hot loops — kernel boundaries are the cheap barrier (~10us).
//
// Numerics replicate the reference EXACTLY in fp32 (absmax=0 in R1-R10):
//   sq  = (x*x + y*y) + z*z               (left-to-right)
//   dot = fma(z,z', fma(y,y', x*x'))      (BLAS k-ordered FMA chain)
//   d2  = (sq_i + sq_j) - 2.0f*dot ; adj = d2 < 0.04f

#define N_PTS   16384
#define BLOCK   256
#define IPT     4
#define ITILE   1024                    // IPT * BLOCK
#define JT      128
#define NTI     (N_PTS / ITILE)         // 16
#define NBLK    (4 * NTI * (NTI + 1))   // 1088 triangular tiles
#define EPS2    0.04f
#define MINPTS  10
#define ECAP    262144
#define CCAP    262144
#define MCAP    65536
#define SCAP    131072
#define BCAP    131072
#define LBUF    1024
#define NCC     1024
#define CHUNK   (N_PTS / NCC)           // 16
#define BIG     N_PTS                   // border sentinel in LDS parent
#define ENCB    16400                   // cluster-code base (> BIG)
#define HUGEV   (1 << 29)               // noise sentinel after re-encoding

__device__ __forceinline__ float sqsum(float x, float y, float z) {
    return __fadd_rn(__fadd_rn(__fmul_rn(x, x), __fmul_rn(y, y)), __fmul_rn(z, z));
}
__device__ __forceinline__ float dist2(float px, float py, float pz, float sqi, float4 q) {
    float dot = __fmaf_rn(pz, q.z, __fmaf_rn(py, q.y, __fmul_rn(px, q.x)));
    return __fsub_rn(__fadd_rn(sqi, q.w), __fmul_rn(2.0f, dot));
}
__device__ __forceinline__ int pload(const int* p) {
    return __hip_atomic_load(p, __ATOMIC_RELAXED, __HIP_MEMORY_SCOPE_AGENT);
}

// ---------------------------------------------------------------------------
__global__ void k_init(int* __restrict__ deg, int* __restrict__ parent,
                       int* __restrict__ cnts) {
    int i = blockIdx.x * BLOCK + threadIdx.x;
    deg[i] = 1;            // self-neighbor (d=0 < eps)
    parent[i] = i;
    if (i < 8) cnts[i] = 0;   // 0=gcnt 1=ccnt 2=mcnt 3=scnt
}

// Packed triangular N^2: i-tile 1024, j-tile 128 (R7 verbatim).
__global__ void k_edges(const float* __restrict__ pts,
                        uint32_t* __restrict__ edges, int* __restrict__ gcnt,
                        int* __restrict__ deg) {
    int b = blockIdx.x;
    float t = sqrtf((float)b + 1.0f);
    int bi = (int)((t - 1.0f) * 0.5f);
    while (4 * (bi + 1) * (bi + 2) <= b) ++bi;
    while (4 * bi * (bi + 1) > b) --bi;
    int jc = b - 4 * bi * (bi + 1);
    const int i0 = bi * ITILE, j0 = jc * JT;
    const bool diag = (jc >= 8 * bi);

    __shared__ float4 sj[JT];
    __shared__ int sdeg[JT];
    __shared__ uint32_t lbuf[LBUF];
    __shared__ int lcnt, lbase;
    const int tid = threadIdx.x;
    if (tid == 0) lcnt = 0;
    if (tid < JT) {
        int j = j0 + tid;
        float x = pts[3 * j], y = pts[3 * j + 1], z = pts[3 * j + 2];
        sj[tid] = make_float4(x, y, z, sqsum(x, y, z));
        sdeg[tid] = 0;
    }
    __syncthreads();
    float px[IPT], py[IPT], pz[IPT], sqi[IPT];
    int ii[IPT], cnt[IPT];
#pragma unroll
    for (int k = 0; k < IPT; ++k) {
        int i = i0 + k * BLOCK + tid;
        ii[k] = i;
        px[k] = pts[3 * i]; py[k] = pts[3 * i + 1]; pz[k] = pts[3 * i + 2];
        sqi[k] = sqsum(px[k], py[k], pz[k]);
        cnt[k] = 0;
    }
    if (!diag) {                                  // jg < i guaranteed
#pragma unroll 4
        for (int j = 0; j < JT; ++j) {
            float4 q = sj[j];
            int jg = j0 + j;
#pragma unroll
            for (int k = 0; k < IPT; ++k) {
                float d2 = dist2(px[k], py[k], pz[k], sqi[k], q);
                if (d2 < EPS2) {
                    int s = atomicAdd(&lcnt, 1);
                    if (s < LBUF) lbuf[s] = ((uint32_t)ii[k] << 14) | (uint32_t)jg;
                    ++cnt[k];
                    atomicAdd(&sdeg[j], 1);
                }
            }
        }
    } else {
#pragma unroll 4
        for (int j = 0; j < JT; ++j) {
            float4 q = sj[j];
            int jg = j0 + j;
#pragma unroll
            for (int k = 0; k < IPT; ++k) {
                float d2 = dist2(px[k], py[k], pz[k], sqi[k], q);
                if (d2 < EPS2 && jg < ii[k]) {
                    int s = atomicAdd(&lcnt, 1);
                    if (s < LBUF) lbuf[s] = ((uint32_t)ii[k] << 14) | (uint32_t)jg;
                    ++cnt[k];
                    atomicAdd(&sdeg[j], 1);
                }
            }
        }
    }
#pragma unroll
    for (int k = 0; k < IPT; ++k)
        if (cnt[k]) atomicAdd(&deg[ii[k]], cnt[k]);
    __syncthreads();
    if (tid < JT && sdeg[tid]) atomicAdd(&deg[j0 + tid], sdeg[tid]);
    if (tid == 0) {
        int n = min(lcnt, LBUF);
        lcnt = n;
        lbase = atomicAdd(gcnt, n);
    }
    __syncthreads();
    for (int t2 = tid; t2 < lcnt; t2 += BLOCK) {
        int s = lbase + t2;
        if (s < ECAP) edges[s] = lbuf[t2];
    }
}

// Full-grid: classify raw edges via deg; hook core-core; build cclist + mbuf.
__global__ void k_hook0(const uint32_t* __restrict__ edges, const int* __restrict__ gcnt,
                        const int* __restrict__ deg, int* __restrict__ parent,
                        uint32_t* __restrict__ cclist, int* __restrict__ ccnt,
                        uint32_t* __restrict__ mbuf, int* __restrict__ mcnt) {
    const int n = min(pload(gcnt), ECAP);
    const int lane = threadIdx.x & 63;
    const uint64_t lane_lt = (1ull << lane) - 1;
    for (int e = blockIdx.x * BLOCK + threadIdx.x; e < n; e += gridDim.x * BLOCK) {
        uint32_t p = edges[e];
        int i = (int)(p >> 14), j = (int)(p & (N_PTS - 1));
        bool ci = deg[i] >= MINPTS, cj = deg[j] >= MINPTS;
        bool cc = ci && cj, mx = ci != cj;
        if (cc) atomicMin(&parent[max(i, j)], min(i, j));  // fire-and-forget
        uint64_t m1 = __ballot(cc);
        if (m1) {
            int ldr = (int)__ffsll((unsigned long long)m1) - 1;
            int base = 0;
            if (lane == ldr) base = atomicAdd(ccnt, (int)__popcll(m1));
            base = __shfl(base, ldr);
            if (cc) {
                int pos = base + (int)__popcll(m1 & lane_lt);
                if (pos < CCAP) cclist[pos] = p;
            }
        }
        uint64_t m2 = __ballot(mx);
        if (m2) {
            int ldr = (int)__ffsll((unsigned long long)m2) - 1;
            int base = 0;
            if (lane == ldr) base = atomicAdd(mcnt, (int)__popcll(m2));
            base = __shfl(base, ldr);
            if (mx) {
                uint32_t pk = ci ? (((uint32_t)i << 14) | (uint32_t)j)
                                 : (((uint32_t)j << 14) | (uint32_t)i);  // core<<14|border
                int pos = base + (int)__popcll(m2 & lane_lt);
                if (pos < MCAP) mbuf[pos] = pk;
            }
        }
    }
}

// One chase per node: parent[x] = root(x). Flat tree for k_hook1's flat reads.
__global__ void k_jump(int* __restrict__ parent) {
    int x = blockIdx.x * BLOCK + threadIdx.x;
    int p = pload(&parent[x]);
    if (p == x) return;
    int r = p;
    while (true) { int q = pload(&parent[r]); if (q == r) break; r = q; }
    if (r != p)
        __hip_atomic_store(&parent[x], r, __ATOMIC_RELAXED, __HIP_MEMORY_SCOPE_AGENT);
}

// Flat-read root pairs, hook, append still-differing survivors.
__global__ void k_hook1(const uint32_t* __restrict__ cclist, const int* __restrict__ ccnt,
                        int* __restrict__ parent,
                        uint32_t* __restrict__ surv, int* __restrict__ scnt) {
    const int n = min(pload(ccnt), CCAP);
    const int lane = threadIdx.x & 63;
    const uint64_t lane_lt = (1ull << lane) - 1;
    for (int e = blockIdx.x * BLOCK + threadIdx.x; e < n; e += gridDim.x * BLOCK) {
        uint32_t p = cclist[e];
        int ri = pload(&parent[(int)(p >> 14)]);       // flat read (post-jump)
        int rj = pload(&parent[(int)(p & (N_PTS - 1))]);
        bool live = (ri != rj);
        int lo = min(ri, rj), hi = max(ri, rj);
        if (live) atomicMin(&parent[hi], lo);
        uint64_t m = __ballot(live);
        if (m) {
            int ldr = (int)__ffsll((unsigned long long)m) - 1;
            int base = 0;
            if (lane == ldr) base = atomicAdd(scnt, (int)__popcll(m));
            base = __shfl(base, ldr);
            if (live) {
                int pos = base + (int)__popcll(m & lane_lt);
                if (pos < SCAP) surv[pos] = ((uint32_t)hi << 14) | (uint32_t)lo;
            }
        }
    }
}

// ---------------------------------------------------------------------------
__global__ void __launch_bounds__(NCC)
k_cc_final(const int* __restrict__ parent_g, const int* __restrict__ deg,
           const uint32_t* __restrict__ surv, const int* __restrict__ scnt,
           const uint32_t* __restrict__ mbuf, const int* __restrict__ mcnt,
           uint32_t* __restrict__ bufA, uint32_t* __restrict__ bufB,
           float* __restrict__ out) {
    __shared__ int parent[N_PTS];                  // 64 KB
    __shared__ int s_nout;
    __shared__ int wsum[16];
    const int tid = threadIdx.x, lane = tid & 63, wv = tid >> 6;
    const uint64_t lane_lt = (1ull << lane) - 1;

#pragma unroll
    for (int k = 0; k < CHUNK; ++k) {
        int x = k * NCC + tid;                     // coalesced
        parent[x] = (deg[x] >= MINPTS) ? parent_g[x] : BIG;
    }
    __syncthreads();
    // initial compress: wavefront chase, 16 independent streams per thread
    {
        int v[CHUNK];
#pragma unroll
        for (int k = 0; k < CHUNK; ++k) v[k] = parent[k * NCC + tid];
        bool any = true;
        while (any) {
            any = false;
#pragma unroll
            for (int k = 0; k < CHUNK; ++k) {
                if (v[k] < BIG) {
                    int q = parent[v[k]];
                    if (q != v[k]) { v[k] = q; any = true; }
                }
            }
        }
#pragma unroll
        for (int k = 0; k < CHUNK; ++k)
            if (v[k] < BIG) parent[k * NCC + tid] = v[k];
    }
    __syncthreads();

    // contraction rounds to exact fixpoint over the survivor list
    int n_in = min(pload(scnt), SCAP);
    const uint32_t* cur = surv;
    for (int r = 0; r < 24; ++r) {
        uint32_t* nxt = (r & 1) ? bufB : bufA;
        if (tid == 0) s_nout = 0;
        __syncthreads();
        const int n4 = (n_in + 3) & ~3;
        for (int bb = tid * 4; bb < n4; bb += NCC * 4) {
            uint4 pk = *(const uint4*)(cur + bb);
#pragma unroll
            for (int k = 0; k < 4; ++k) {
                uint32_t p = (k == 0) ? pk.x : (k == 1) ? pk.y : (k == 2) ? pk.z : pk.w;
                bool valid = (bb + k) < n_in;
                int ri = 0, rj = 0;
                if (valid) {
                    ri = parent[(int)(p >> 14)];
                    rj = parent[(int)(p & (N_PTS - 1))];
                }
                bool live = valid && (ri != rj);
                int lo = min(ri, rj), hi = max(ri, rj);
                if (live) atomicMin(&parent[hi], lo);       // LDS fire-and-forget
                uint64_t m = __ballot(live);
                if (m) {
                    int ldr = (int)__ffsll((unsigned long long)m) - 1;
                    int base = 0;
                    if (lane == ldr) base = atomicAdd(&s_nout, (int)__popcll(m));
                    base = __shfl(base, ldr);
                    if (live) {
                        int pos = base + (int)__popcll(m & lane_lt);
                        if (pos < BCAP) nxt[pos] = ((uint32_t)hi << 14) | (uint32_t)lo;
                    }
                }
            }
        }
        __syncthreads();
        int v[CHUNK];
#pragma unroll
        for (int k = 0; k < CHUNK; ++k) v[k] = parent[k * NCC + tid];
        bool any = true;
        while (any) {
            any = false;
#pragma unroll
            for (int k = 0; k < CHUNK; ++k) {
                if (v[k] < BIG) {
                    int q = parent[v[k]];
                    if (q != v[k]) { v[k] = q; any = true; }
                }
            }
        }
#pragma unroll
        for (int k = 0; k < CHUNK; ++k)
            if (v[k] < BIG) parent[k * NCC + tid] = v[k];
        __syncthreads();
        if (s_nout == 0) break;                    // uniform
        n_in = min(s_nout, BCAP);
        cur = nxt;
    }

    // D1: rank roots ascending; re-encode root slots in place as ENCB+rank
    const int bn = tid * CHUNK;
    int fl[CHUNK]; int s = 0;
#pragma unroll
    for (int k = 0; k < CHUNK; ++k) {
        fl[k] = (parent[bn + k] == bn + k) ? 1 : 0;   // borders hold BIG != index
        s += fl[k];
    }
    int incl = s;
#pragma unroll
    for (int d = 1; d < 64; d <<= 1) { int t = __shfl_up(incl, d, 64); if (lane >= d) incl += t; }
    if (lane == 63) wsum[wv] = incl;
    __syncthreads();
    int wbase = 0;
    for (int w = 0; w < wv; ++w) wbase += wsum[w];
    int c = wbase + incl - s;
#pragma unroll
    for (int k = 0; k < CHUNK; ++k)
        if (fl[k]) parent[bn + k] = ENCB + (c++);
    __syncthreads();
    // D2: non-root cores -> root's code; borders -> HUGE sentinel
#pragma unroll
    for (int k = 0; k < CHUNK; ++k) {
        int x = k * NCC + tid;
        int p = parent[x];
        if (p < BIG) parent[x] = parent[p];        // root slots stable (>= ENCB)
        else if (p == BIG) parent[x] = HUGEV;
    }
    __syncthreads();
    // C: border labels = min neighbor-cluster code (rank monotone in root)
    int nm = min(pload(mcnt), MCAP);
    for (int e = tid; e < nm; e += NCC) {
        uint32_t p = mbuf[e];
        int cc = (int)(p >> 14), bb = (int)(p & (N_PTS - 1));
        atomicMin(&parent[bb], parent[cc]);        // LDS
    }
    __syncthreads();
    // E: labels
#pragma unroll
    for (int k = 0; k < CHUNK; ++k) {
        int x = k * NCC + tid;                     // coalesced store
        int v = parent[x];
        out[x] = (v < HUGEV) ? (float)(v - ENCB) : -1.0f;
    }
}

// ---------------------------------------------------------------------------
extern "C" void kernel_launch(void* const* d_in, const int* in_sizes, int n_in,
                              void* d_out, int out_size, void* d_ws, size_t ws_size,
                              hipStream_t stream) {
    (void)in_sizes; (void)n_in; (void)out_size; (void)ws_size;
    const float* pts = (const float*)d_in[0];
    float* out = (float*)d_out;

    // ws layout (words; all list offsets multiples of 16 -> uint4-safe)
    int* ib = (int*)d_ws;
    int*      deg    = ib;                         // 16384
    int*      parent = deg + N_PTS;                // 16384
    int*      cnts   = parent + N_PTS;             // 64
    int*      gcnt = cnts + 0, *ccnt = cnts + 1, *mcnt = cnts + 2, *scnt = cnts + 3;
    uint32_t* edges  = (uint32_t*)(cnts + 64);     // 262144
    uint32_t* cclist = edges + ECAP;               // 262144
    uint32_t* mbuf   = cclist + CCAP;              // 65536
    uint32_t* surv   = mbuf + MCAP;                // 131072
    uint32_t* bufA   = surv + SCAP;                // 131072
    uint32_t* bufB   = bufA + BCAP;                // 131072  (~3.7 MB total)

    dim3 blk(BLOCK);
    dim3 gN(N_PTS / BLOCK);                        // 64
    k_init    <<<gN, blk, 0, stream>>>(deg, parent, cnts);
    k_edges   <<<dim3(NBLK), blk, 0, stream>>>(pts, edges, gcnt, deg);
    k_hook0   <<<dim3(1024), blk, 0, stream>>>(edges, gcnt, deg, parent,
                                               cclist, ccnt, mbuf, mcnt);
    k_jump    <<<gN, blk, 0, stream>>>(parent);
    k_hook1   <<<dim3(1024), blk, 0, stream>>>(cclist, ccnt, parent, surv, scnt);
    k_cc_final<<<dim3(1), dim3(NCC), 0, stream>>>(parent, deg, surv, scnt,
                                                  mbuf, mcnt, bufA, bufB, out);
}